// Round 12
// baseline (333.914 us; speedup 1.0000x reference)
//
#include <hip/hip_runtime.h>
#include <hip/hip_bf16.h>
#include <hip/hip_fp16.h>

#define N_NODES 50000
#define N_EDGES 800000
#define NUM_GRAPHS 256
#define D 64
#define EPS 1e-5f
#define N_PART 8
#define PART_SIZE (N_NODES / N_PART)   // 6250
#define SCAT_CHUNKS 512

// ---------------------------------------------------------------------------
// 1) one-pass slotted-CSR build, XCD-partitioned by destination range.
__global__ __launch_bounds__(256) void scatter_cnt_kernel(
        const int* __restrict__ ei, int* __restrict__ cnt,
        unsigned short* __restrict__ ssrc, int cap, int E) {
    int p     = blockIdx.x & (N_PART - 1);
    int chunk = blockIdx.x >> 3;
    int per   = (E + SCAT_CHUNKS - 1) / SCAT_CHUNKS;
    int lo    = chunk * per;
    int hi    = lo + per; if (hi > E) hi = E;
    for (int e = lo + threadIdx.x; e < hi; e += 256) {
        int c = ei[E + e];
        if (c / PART_SIZE == p) {
            int r = ei[e];
            int pos = atomicAdd(&cnt[c], 1);
            if (pos < cap) ssrc[(size_t)c * cap + pos] = (unsigned short)r;
        }
    }
}

// 2) Yh[N,64](fp16) = dinv[row] * (X[N,64] @ W[64,64]) — 64-row tile, 4x4 reg
//    blocking, fp32 accumulate.
__global__ __launch_bounds__(256) void gemm64_kernel(const float* __restrict__ X,
                                                     const float* __restrict__ W,
                                                     const int* __restrict__ cnt,
                                                     __half* __restrict__ Yh, int N) {
    __shared__ float Ws[64 * 64];     // row k, col c
    __shared__ float Xs[64 * 65];     // row r (padded), col k
    int base = blockIdx.x * 64;
    for (int i = threadIdx.x; i < 1024; i += 256)
        ((float4*)Ws)[i] = ((const float4*)W)[i];
    for (int i = threadIdx.x; i < 1024; i += 256) {
        int rr = i >> 4, cc = (i & 15) * 4;
        float4 xv = (base + rr < N)
            ? ((const float4*)X)[(size_t)(base + rr) * 16 + (i & 15)]
            : make_float4(0.f, 0.f, 0.f, 0.f);
        float* dst = &Xs[rr * 65 + cc];
        dst[0] = xv.x; dst[1] = xv.y; dst[2] = xv.z; dst[3] = xv.w;
    }
    __syncthreads();
    int rg = (threadIdx.x >> 4) * 4;        // rows rg..rg+3
    int cg = (threadIdx.x & 15) * 4;        // cols cg..cg+3
    float4 a0 = make_float4(0.f,0.f,0.f,0.f);
    float4 a1 = a0, a2 = a0, a3 = a0;
#pragma unroll
    for (int k = 0; k < 64; k++) {
        float4 wv = *(const float4*)&Ws[k * 64 + cg];
        float x0 = Xs[(rg + 0) * 65 + k];
        float x1 = Xs[(rg + 1) * 65 + k];
        float x2 = Xs[(rg + 2) * 65 + k];
        float x3 = Xs[(rg + 3) * 65 + k];
        a0.x += x0*wv.x; a0.y += x0*wv.y; a0.z += x0*wv.z; a0.w += x0*wv.w;
        a1.x += x1*wv.x; a1.y += x1*wv.y; a1.z += x1*wv.z; a1.w += x1*wv.w;
        a2.x += x2*wv.x; a2.y += x2*wv.y; a2.z += x2*wv.z; a2.w += x2*wv.w;
        a3.x += x3*wv.x; a3.y += x3*wv.y; a3.z += x3*wv.z; a3.w += x3*wv.w;
    }
#pragma unroll
    for (int j = 0; j < 4; j++) {
        float4 a = (j == 0) ? a0 : (j == 1) ? a1 : (j == 2) ? a2 : a3;
        int row = base + rg + j;
        if (row < N) {
            float ws = rsqrtf((float)cnt[row] + 1.0f);   // dinv[row], baked in
            __half2 p0 = __floats2half2_rn(ws * a.x, ws * a.y);
            __half2 p1 = __floats2half2_rn(ws * a.z, ws * a.w);
            uint2 v;
            v.x = *(unsigned int*)&p0;
            v.y = *(unsigned int*)&p1;
            *((uint2*)&Yh[(size_t)row * 64 + cg]) = v;
        }
    }
}

__device__ __forceinline__ void acc_row(uint4 v, float4& A, float4& B) {
    __half2* hp = (__half2*)&v;
    float2 q0 = __half22float2(hp[0]), q1 = __half22float2(hp[1]);
    float2 q2 = __half22float2(hp[2]), q3 = __half22float2(hp[3]);
    A.x += q0.x; A.y += q0.y; A.z += q1.x; A.w += q1.y;
    B.x += q2.x; B.y += q2.y; B.z += q3.x; B.w += q3.y;
}

// 3) fused slotted-CSR aggregation + self-loop + gcn bias + BN + ReLU.
//    One wave per dest node, STRAIGHT-LINE (no loop): lane=(sub 0..7, f2 0..7);
//    lane's 8 edge indices = ONE uint4 of ushorts; 8 independent masked row
//    gathers issued back-to-back (self-loop as 9th on sub 7) -> ~8 VMEM in
//    flight per wave (vs ~1.7 in the looped form: the MLP-bound fix).
__global__ __launch_bounds__(256) void agg_bn_kernel(
        const __half* __restrict__ xwh, const int* __restrict__ cnt,
        const unsigned short* __restrict__ ssrc, int cap,
        const float* __restrict__ b, const float* __restrict__ g,
        const float* __restrict__ bb, const float* __restrict__ m,
        const float* __restrict__ var,
        float* __restrict__ out, int N) {
    int wave = (blockIdx.x * blockDim.x + threadIdx.x) >> 6;
    int lane = threadIdx.x & 63;
    if (wave >= N) return;
    int c   = wave;
    int sub = lane >> 3;        // 8 edge-slots: this lane covers edges 8*sub..8*sub+7
    int f2  = lane & 7;         // feature group: feats 8*f2 .. 8*f2+7
    const uint4* xw8 = (const uint4*)xwh;
    int n = cnt[c];
    if (n > cap) n = cap;
    float dc = rsqrtf((float)n + 1.0f);
    int e0 = 8 * sub;
    // one 16B load = this lane's 8 candidate edge indices
    uint4 s8 = make_uint4(0, 0, 0, 0);
    if (e0 < n && e0 + 8 <= cap)
        s8 = *(const uint4*)&ssrc[(size_t)c * cap + e0];
    int r0 = s8.x & 0xffff, r1 = s8.x >> 16;
    int r2 = s8.y & 0xffff, r3 = s8.y >> 16;
    int r4 = s8.z & 0xffff, r5 = s8.z >> 16;
    int r6 = s8.w & 0xffff, r7 = s8.w >> 16;
    const uint4 z4 = make_uint4(0, 0, 0, 0);
    // 9 independent masked gathers, all in flight before any consume
    uint4 v0 = (e0 + 0 < n) ? xw8[(size_t)r0 * 8 + f2] : z4;
    uint4 v1 = (e0 + 1 < n) ? xw8[(size_t)r1 * 8 + f2] : z4;
    uint4 v2 = (e0 + 2 < n) ? xw8[(size_t)r2 * 8 + f2] : z4;
    uint4 v3 = (e0 + 3 < n) ? xw8[(size_t)r3 * 8 + f2] : z4;
    uint4 v4 = (e0 + 4 < n) ? xw8[(size_t)r4 * 8 + f2] : z4;
    uint4 v5 = (e0 + 5 < n) ? xw8[(size_t)r5 * 8 + f2] : z4;
    uint4 v6 = (e0 + 6 < n) ? xw8[(size_t)r6 * 8 + f2] : z4;
    uint4 v7 = (e0 + 7 < n) ? xw8[(size_t)r7 * 8 + f2] : z4;
    uint4 vs = (sub == 7)   ? xw8[(size_t)c  * 8 + f2] : z4;   // self-loop row
    float4 accA = make_float4(0.f, 0.f, 0.f, 0.f);
    float4 accB = accA;
    acc_row(v0, accA, accB); acc_row(v1, accA, accB);
    acc_row(v2, accA, accB); acc_row(v3, accA, accB);
    acc_row(v4, accA, accB); acc_row(v5, accA, accB);
    acc_row(v6, accA, accB); acc_row(v7, accA, accB);
    acc_row(vs, accA, accB);
    // butterfly-reduce over sub (lane bits 3,4,5); all lanes end with full sums
#pragma unroll
    for (int off = 8; off < 64; off <<= 1) {
        accA.x += __shfl_xor(accA.x, off, 64); accA.y += __shfl_xor(accA.y, off, 64);
        accA.z += __shfl_xor(accA.z, off, 64); accA.w += __shfl_xor(accA.w, off, 64);
        accB.x += __shfl_xor(accB.x, off, 64); accB.y += __shfl_xor(accB.y, off, 64);
        accB.z += __shfl_xor(accB.z, off, 64); accB.w += __shfl_xor(accB.w, off, 64);
    }
    if (sub < 2) {   // BN+ReLU epilogue split across 2 subs (2 float4s per node-f2)
        int i4 = 2 * f2 + sub;
        float4 acc = sub ? accB : accA;
        float4 b4  = ((const float4*)b)[i4];
        float4 m4  = ((const float4*)m)[i4];
        float4 v4_ = ((const float4*)var)[i4];
        float4 g4  = ((const float4*)g)[i4];
        float4 bb4 = ((const float4*)bb)[i4];
        float4 h;
        h.x = (acc.x * dc + b4.x - m4.x) * (1.0f / sqrtf(v4_.x + EPS)) * g4.x + bb4.x;
        h.y = (acc.y * dc + b4.y - m4.y) * (1.0f / sqrtf(v4_.y + EPS)) * g4.y + bb4.y;
        h.z = (acc.z * dc + b4.z - m4.z) * (1.0f / sqrtf(v4_.z + EPS)) * g4.z + bb4.z;
        h.w = (acc.w * dc + b4.w - m4.w) * (1.0f / sqrtf(v4_.w + EPS)) * g4.w + bb4.w;
        h.x = h.x > 0.f ? h.x : 0.f;
        h.y = h.y > 0.f ? h.y : 0.f;
        h.z = h.z > 0.f ? h.z : 0.f;
        h.w = h.w > 0.f ? h.w : 0.f;
        ((float4*)out)[(size_t)c * 16 + i4] = h;
    }
}

// 4) fused mean-pool (via sorted-batch binary search) + full MLP head.
__global__ __launch_bounds__(256) void pool_head_kernel(
        const float* __restrict__ h, const int* __restrict__ batch,
        const float* __restrict__ hW1, const float* __restrict__ hb1,
        const float* __restrict__ hg1, const float* __restrict__ hbb1,
        const float* __restrict__ hm1, const float* __restrict__ hv1,
        const float* __restrict__ hW2, const float* __restrict__ hb2,
        const float* __restrict__ hg2, const float* __restrict__ hbb2,
        const float* __restrict__ hm2, const float* __restrict__ hv2,
        const float* __restrict__ hW3, const float* __restrict__ hb3,
        const float* __restrict__ hW4, const float* __restrict__ hb4,
        float* __restrict__ out) {
    __shared__ int se[2];
    __shared__ float red[256];
    __shared__ float pooled[64];
    __shared__ float z1[256];
    __shared__ float z2[128];
    __shared__ float z3[64];
    int g = blockIdx.x;
    int t = threadIdx.x;
    if (t < 2) {
        int target = g + t;
        int lo = 0, hi = N_NODES;
        while (lo < hi) {
            int mid = (lo + hi) >> 1;
            if (batch[mid] < target) lo = mid + 1; else hi = mid;
        }
        se[t] = lo;
    }
    __syncthreads();
    int start = se[0], end = se[1];
    {   // mean pool: 4 row-groups x 64 features
        int f = t & 63, rg = t >> 6;
        float part = 0.0f;
        for (int r = start + rg; r < end; r += 4) part += h[(size_t)r * 64 + f];
        red[t] = part;
        __syncthreads();
        if (t < 64) {
            float s = red[t] + red[t + 64] + red[t + 128] + red[t + 192];
            float cnt = (float)(end - start);
            cnt = cnt > 1.0f ? cnt : 1.0f;
            pooled[t] = s / cnt;
        }
    }
    __syncthreads();
    {   // layer 1: 64 -> 256, BN + relu
        float acc = hb1[t];
#pragma unroll
        for (int k = 0; k < 64; k++) acc += pooled[k] * hW1[k * 256 + t];
        acc = (acc - hm1[t]) * (1.0f / sqrtf(hv1[t] + EPS)) * hg1[t] + hbb1[t];
        z1[t] = acc > 0.0f ? acc : 0.0f;
    }
    __syncthreads();
    if (t < 128) {  // layer 2: 256 -> 128, BN + relu
        float acc = hb2[t];
#pragma unroll 8
        for (int k = 0; k < 256; k++) acc += z1[k] * hW2[k * 128 + t];
        acc = (acc - hm2[t]) * (1.0f / sqrtf(hv2[t] + EPS)) * hg2[t] + hbb2[t];
        z2[t] = acc > 0.0f ? acc : 0.0f;
    }
    __syncthreads();
    if (t < 64) {   // layer 3: 128 -> 64, relu
        float acc = hb3[t];
#pragma unroll 8
        for (int k = 0; k < 128; k++) acc += z2[k] * hW3[k * 64 + t];
        z3[t] = acc > 0.0f ? acc : 0.0f;
    }
    __syncthreads();
    if (t < 64) {   // layer 4: 64 -> 1, wave reduce
        float v = z3[t] * hW4[t];
        for (int off = 32; off > 0; off >>= 1) v += __shfl_down(v, off, 64);
        if (t == 0) out[g] = v + hb4[0];
    }
}

extern "C" void kernel_launch(void* const* d_in, const int* in_sizes, int n_in,
                              void* d_out, int out_size, void* d_ws, size_t ws_size,
                              hipStream_t stream) {
    const float* x     = (const float*)d_in[0];
    const int*   ei    = (const int*)d_in[1];   // [2, E] int32
    const int*   batch = (const int*)d_in[2];
    const float* W0 = (const float*)d_in[3];
    const float* b0 = (const float*)d_in[4];
    const float* g0 = (const float*)d_in[5];
    const float* bb0 = (const float*)d_in[6];
    const float* m0 = (const float*)d_in[7];
    const float* v0 = (const float*)d_in[8];
    const float* W1 = (const float*)d_in[9];
    const float* b1 = (const float*)d_in[10];
    const float* g1 = (const float*)d_in[11];
    const float* bb1 = (const float*)d_in[12];
    const float* m1 = (const float*)d_in[13];
    const float* v1 = (const float*)d_in[14];
    const float* hW1 = (const float*)d_in[15];
    const float* hb1 = (const float*)d_in[16];
    const float* hg1 = (const float*)d_in[17];
    const float* hbb1 = (const float*)d_in[18];
    const float* hm1 = (const float*)d_in[19];
    const float* hv1 = (const float*)d_in[20];
    const float* hW2 = (const float*)d_in[21];
    const float* hb2 = (const float*)d_in[22];
    const float* hg2 = (const float*)d_in[23];
    const float* hbb2 = (const float*)d_in[24];
    const float* hm2 = (const float*)d_in[25];
    const float* hv2 = (const float*)d_in[26];
    const float* hW3 = (const float*)d_in[27];
    const float* hb3 = (const float*)d_in[28];
    const float* hW4 = (const float*)d_in[29];
    const float* hb4 = (const float*)d_in[30];
    float* out = (float*)d_out;

    // workspace layout (d_ws is 16B-aligned)
    float*  bufA = (float*)d_ws;                         // N*64 floats (fp16 table lives here)
    __half* xwh  = (__half*)bufA;
    float*  bufB = bufA + (size_t)N_NODES * D;           // N*64 floats (node features)
    int*    cnt  = (int*)(bufB + (size_t)N_NODES * D);   // N
    unsigned short* ssrc = (unsigned short*)(cnt + N_NODES);  // N*cap ushorts

    // slot capacity: prefer 64 (straight-line agg assumes cap==64 when space allows)
    size_t used  = ((size_t)2 * N_NODES * D + N_NODES) * 4;
    int cap = 64;
    if (ws_size >= used) {
        size_t avail = (ws_size - used) / ((size_t)N_NODES * 2);
        if (avail < (size_t)cap) cap = (int)avail & ~7;  // multiple of 8
    } else {
        cap = 0;  // should not happen; avoids OOB
    }

    const int NT = 256;
    hipMemsetAsync(cnt, 0, (size_t)N_NODES * 4, stream);

    // one-pass XCD-partitioned slotted-CSR build
    scatter_cnt_kernel<<<SCAT_CHUNKS * N_PART, NT, 0, stream>>>(ei, cnt, ssrc, cap, N_EDGES);

    // layer 0
    gemm64_kernel<<<(N_NODES + 63) / 64, NT, 0, stream>>>(x, W0, cnt, xwh, N_NODES);
    agg_bn_kernel<<<(N_NODES * 64 + NT - 1) / NT, NT, 0, stream>>>(
        xwh, cnt, ssrc, cap, b0, g0, bb0, m0, v0, bufB, N_NODES);

    // layer 1
    gemm64_kernel<<<(N_NODES + 63) / 64, NT, 0, stream>>>(bufB, W1, cnt, xwh, N_NODES);
    agg_bn_kernel<<<(N_NODES * 64 + NT - 1) / NT, NT, 0, stream>>>(
        xwh, cnt, ssrc, cap, b1, g1, bb1, m1, v1, bufB, N_NODES);

    // mean pool + MLP head (fused)
    pool_head_kernel<<<NUM_GRAPHS, NT, 0, stream>>>(bufB, batch,
        hW1, hb1, hg1, hbb1, hm1, hv1,
        hW2, hb2, hg2, hbb2, hm2, hv2,
        hW3, hb3, hW4, hb4, out);
}

// Round 13
// 265.668 us; speedup vs baseline: 1.2569x; 1.2569x over previous
//
#include <hip/hip_runtime.h>
#include <hip/hip_bf16.h>
#include <hip/hip_fp16.h>

#define N_NODES 50000
#define N_EDGES 800000
#define NUM_GRAPHS 256
#define D 64
#define EPS 1e-5f
#define N_PART 8
#define PART_SIZE (N_NODES / N_PART)   // 6250
#define SCAT_CHUNKS 512
#define WP 72   // padded LDS row stride in halves (16B-aligned, conflict-breaking)

typedef _Float16 half8_t __attribute__((ext_vector_type(8)));
typedef float f32x4 __attribute__((ext_vector_type(4)));

// ---------------------------------------------------------------------------
// 1) one-pass slotted-CSR build, XCD-partitioned by destination range.
__global__ __launch_bounds__(256) void scatter_cnt_kernel(
        const int* __restrict__ ei, int* __restrict__ cnt,
        unsigned short* __restrict__ ssrc, int cap, int E) {
    int p     = blockIdx.x & (N_PART - 1);
    int chunk = blockIdx.x >> 3;
    int per   = (E + SCAT_CHUNKS - 1) / SCAT_CHUNKS;
    int lo    = chunk * per;
    int hi    = lo + per; if (hi > E) hi = E;
    for (int e = lo + threadIdx.x; e < hi; e += 256) {
        int c = ei[E + e];
        if (c / PART_SIZE == p) {
            int r = ei[e];
            int pos = atomicAdd(&cnt[c], 1);
            if (pos < cap) ssrc[(size_t)c * cap + pos] = (unsigned short)r;
        }
    }
}

// 2) MFMA GEMM: Yh[N,64](fp16) = dinv[row] * (X[N,64] @ W[64,64]).
//    64-row tile/block; X,W^T staged as fp16 in LDS (stride WP=72 halves:
//    16B-aligned frags, A-frag reads 2-way-conflict only). 4 waves x 16 rows,
//    8x mfma_f32_16x16x32_f16 per wave, fp32 accum, fused dinv + fp16 store.
//    Frag layout (HW-verified m89): A[m=lane&15][k=(lane>>4)*8+j],
//    B[k][n] from W^T row n; D[row=(lane>>4)*4+reg][col=lane&15].
__global__ __launch_bounds__(256) void gemm64_kernel(const float* __restrict__ X,
                                                     const float* __restrict__ W,
                                                     const int* __restrict__ cnt,
                                                     __half* __restrict__ Yh, int N) {
    __shared__ _Float16 Xs[64 * WP];   // [row][k]
    __shared__ _Float16 Wt[64 * WP];   // [n][k]  (W transposed)
    int tid  = threadIdx.x;
    int base = blockIdx.x * 64;
    // stage W^T -> fp16 (coalesced read W[i], i = k*64+n)
    for (int i = tid; i < 4096; i += 256) {
        int k = i >> 6, n = i & 63;
        Wt[n * WP + k] = (_Float16)W[i];
    }
    // stage X rows -> fp16
    for (int i = tid; i < 1024; i += 256) {
        int r = i >> 4, c4 = (i & 15) * 4;
        float4 xv = (base + r < N)
            ? ((const float4*)X)[(size_t)(base + r) * 16 + (i & 15)]
            : make_float4(0.f, 0.f, 0.f, 0.f);
        _Float16* dst = &Xs[r * WP + c4];
        dst[0] = (_Float16)xv.x; dst[1] = (_Float16)xv.y;
        dst[2] = (_Float16)xv.z; dst[3] = (_Float16)xv.w;
    }
    __syncthreads();
    int wave  = tid >> 6;          // 0..3 -> rows wave*16..+15
    int lane  = tid & 63;
    int m     = lane & 15;         // A row in tile / D col
    int q     = lane >> 4;         // quad
    int row16 = wave * 16;
    half8_t a0 = *(const half8_t*)&Xs[(row16 + m) * WP + q * 8];
    half8_t a1 = *(const half8_t*)&Xs[(row16 + m) * WP + 32 + q * 8];
    f32x4 acc[4];
#pragma unroll
    for (int ct = 0; ct < 4; ct++) {
        half8_t b0 = *(const half8_t*)&Wt[(ct * 16 + m) * WP + q * 8];
        half8_t b1 = *(const half8_t*)&Wt[(ct * 16 + m) * WP + 32 + q * 8];
        f32x4 c = {0.f, 0.f, 0.f, 0.f};
        c = __builtin_amdgcn_mfma_f32_16x16x32_f16(a0, b0, c, 0, 0, 0);
        c = __builtin_amdgcn_mfma_f32_16x16x32_f16(a1, b1, c, 0, 0, 0);
        acc[ct] = c;
    }
    // epilogue: row = base+row16+q*4+reg, col = ct*16+m
    int   rows[4];
    float ws[4];
#pragma unroll
    for (int reg = 0; reg < 4; reg++) {
        rows[reg] = base + row16 + q * 4 + reg;
        ws[reg] = (rows[reg] < N) ? rsqrtf((float)cnt[rows[reg]] + 1.0f) : 0.0f;
    }
#pragma unroll
    for (int ct = 0; ct < 4; ct++) {
#pragma unroll
        for (int reg = 0; reg < 4; reg++) {
            if (rows[reg] < N)
                Yh[(size_t)rows[reg] * 64 + ct * 16 + m] =
                    (__half)(ws[reg] * acc[ct][reg]);
        }
    }
}

// 3) fused slotted-CSR aggregation + self-loop + gcn bias + BN + ReLU.
//    R11 looped form (best measured). Lane = (edge-sub 0..7, feat-group 0..7).
__global__ __launch_bounds__(256) void agg_bn_kernel(
        const __half* __restrict__ xwh, const int* __restrict__ cnt,
        const unsigned short* __restrict__ ssrc, int cap,
        const float* __restrict__ b, const float* __restrict__ g,
        const float* __restrict__ bb, const float* __restrict__ m,
        const float* __restrict__ var,
        float* __restrict__ out, int N) {
    int wave = (blockIdx.x * blockDim.x + threadIdx.x) >> 6;
    int lane = threadIdx.x & 63;
    if (wave >= N) return;
    int c   = wave;
    int sub = lane >> 3;        // which of 8 concurrent edges
    int f2  = lane & 7;         // feature group: feats 8*f2 .. 8*f2+7
    const uint4* xw8 = (const uint4*)xwh;
    int n = cnt[c];
    if (n > cap) n = cap;
    size_t base = (size_t)c * cap;
    float dc = rsqrtf((float)n + 1.0f);
    float4 accA = make_float4(0.f, 0.f, 0.f, 0.f);
    float4 accB = accA;
    if (sub == 0) {  // self-loop: xws[c] already = dc * xw[c]
        uint4 v = xw8[(size_t)c * 8 + f2];
        __half2* hp = (__half2*)&v;
        float2 q0 = __half22float2(hp[0]), q1 = __half22float2(hp[1]);
        float2 q2 = __half22float2(hp[2]), q3 = __half22float2(hp[3]);
        accA.x = q0.x; accA.y = q0.y; accA.z = q1.x; accA.w = q1.y;
        accB.x = q2.x; accB.y = q2.y; accB.z = q3.x; accB.w = q3.y;
    }
    for (int e0 = 0; e0 < n; e0 += 8) {
        int e = e0 + sub;
        if (e < n) {
            int r = (int)ssrc[base + e];
            uint4 v = xw8[(size_t)r * 8 + f2];
            __half2* hp = (__half2*)&v;
            float2 q0 = __half22float2(hp[0]), q1 = __half22float2(hp[1]);
            float2 q2 = __half22float2(hp[2]), q3 = __half22float2(hp[3]);
            accA.x += q0.x; accA.y += q0.y;
            accA.z += q1.x; accA.w += q1.y;
            accB.x += q2.x; accB.y += q2.y;
            accB.z += q3.x; accB.w += q3.y;
        }
    }
#pragma unroll
    for (int off = 8; off < 64; off <<= 1) {
        accA.x += __shfl_xor(accA.x, off, 64); accA.y += __shfl_xor(accA.y, off, 64);
        accA.z += __shfl_xor(accA.z, off, 64); accA.w += __shfl_xor(accA.w, off, 64);
        accB.x += __shfl_xor(accB.x, off, 64); accB.y += __shfl_xor(accB.y, off, 64);
        accB.z += __shfl_xor(accB.z, off, 64); accB.w += __shfl_xor(accB.w, off, 64);
    }
    if (sub < 2) {   // BN+ReLU epilogue split across 2 subs
        int i4 = 2 * f2 + sub;
        float4 acc = sub ? accB : accA;
        float4 b4  = ((const float4*)b)[i4];
        float4 m4  = ((const float4*)m)[i4];
        float4 v4_ = ((const float4*)var)[i4];
        float4 g4  = ((const float4*)g)[i4];
        float4 bb4 = ((const float4*)bb)[i4];
        float4 h;
        h.x = (acc.x * dc + b4.x - m4.x) * (1.0f / sqrtf(v4_.x + EPS)) * g4.x + bb4.x;
        h.y = (acc.y * dc + b4.y - m4.y) * (1.0f / sqrtf(v4_.y + EPS)) * g4.y + bb4.y;
        h.z = (acc.z * dc + b4.z - m4.z) * (1.0f / sqrtf(v4_.z + EPS)) * g4.z + bb4.z;
        h.w = (acc.w * dc + b4.w - m4.w) * (1.0f / sqrtf(v4_.w + EPS)) * g4.w + bb4.w;
        h.x = h.x > 0.f ? h.x : 0.f;
        h.y = h.y > 0.f ? h.y : 0.f;
        h.z = h.z > 0.f ? h.z : 0.f;
        h.w = h.w > 0.f ? h.w : 0.f;
        ((float4*)out)[(size_t)c * 16 + i4] = h;
    }
}

// 4) fused mean-pool (via sorted-batch binary search) + full MLP head.
__global__ __launch_bounds__(256) void pool_head_kernel(
        const float* __restrict__ h, const int* __restrict__ batch,
        const float* __restrict__ hW1, const float* __restrict__ hb1,
        const float* __restrict__ hg1, const float* __restrict__ hbb1,
        const float* __restrict__ hm1, const float* __restrict__ hv1,
        const float* __restrict__ hW2, const float* __restrict__ hb2,
        const float* __restrict__ hg2, const float* __restrict__ hbb2,
        const float* __restrict__ hm2, const float* __restrict__ hv2,
        const float* __restrict__ hW3, const float* __restrict__ hb3,
        const float* __restrict__ hW4, const float* __restrict__ hb4,
        float* __restrict__ out) {
    __shared__ int se[2];
    __shared__ float red[256];
    __shared__ float pooled[64];
    __shared__ float z1[256];
    __shared__ float z2[128];
    __shared__ float z3[64];
    int g = blockIdx.x;
    int t = threadIdx.x;
    if (t < 2) {
        int target = g + t;
        int lo = 0, hi = N_NODES;
        while (lo < hi) {
            int mid = (lo + hi) >> 1;
            if (batch[mid] < target) lo = mid + 1; else hi = mid;
        }
        se[t] = lo;
    }
    __syncthreads();
    int start = se[0], end = se[1];
    {   // mean pool: 4 row-groups x 64 features
        int f = t & 63, rg = t >> 6;
        float part = 0.0f;
        for (int r = start + rg; r < end; r += 4) part += h[(size_t)r * 64 + f];
        red[t] = part;
        __syncthreads();
        if (t < 64) {
            float s = red[t] + red[t + 64] + red[t + 128] + red[t + 192];
            float cnt = (float)(end - start);
            cnt = cnt > 1.0f ? cnt : 1.0f;
            pooled[t] = s / cnt;
        }
    }
    __syncthreads();
    {   // layer 1: 64 -> 256, BN + relu
        float acc = hb1[t];
#pragma unroll
        for (int k = 0; k < 64; k++) acc += pooled[k] * hW1[k * 256 + t];
        acc = (acc - hm1[t]) * (1.0f / sqrtf(hv1[t] + EPS)) * hg1[t] + hbb1[t];
        z1[t] = acc > 0.0f ? acc : 0.0f;
    }
    __syncthreads();
    if (t < 128) {  // layer 2: 256 -> 128, BN + relu
        float acc = hb2[t];
#pragma unroll 8
        for (int k = 0; k < 256; k++) acc += z1[k] * hW2[k * 128 + t];
        acc = (acc - hm2[t]) * (1.0f / sqrtf(hv2[t] + EPS)) * hg2[t] + hbb2[t];
        z2[t] = acc > 0.0f ? acc : 0.0f;
    }
    __syncthreads();
    if (t < 64) {   // layer 3: 128 -> 64, relu
        float acc = hb3[t];
#pragma unroll 8
        for (int k = 0; k < 128; k++) acc += z2[k] * hW3[k * 64 + t];
        z3[t] = acc > 0.0f ? acc : 0.0f;
    }
    __syncthreads();
    if (t < 64) {   // layer 4: 64 -> 1, wave reduce
        float v = z3[t] * hW4[t];
        for (int off = 32; off > 0; off >>= 1) v += __shfl_down(v, off, 64);
        if (t == 0) out[g] = v + hb4[0];
    }
}

extern "C" void kernel_launch(void* const* d_in, const int* in_sizes, int n_in,
                              void* d_out, int out_size, void* d_ws, size_t ws_size,
                              hipStream_t stream) {
    const float* x     = (const float*)d_in[0];
    const int*   ei    = (const int*)d_in[1];   // [2, E] int32
    const int*   batch = (const int*)d_in[2];
    const float* W0 = (const float*)d_in[3];
    const float* b0 = (const float*)d_in[4];
    const float* g0 = (const float*)d_in[5];
    const float* bb0 = (const float*)d_in[6];
    const float* m0 = (const float*)d_in[7];
    const float* v0 = (const float*)d_in[8];
    const float* W1 = (const float*)d_in[9];
    const float* b1 = (const float*)d_in[10];
    const float* g1 = (const float*)d_in[11];
    const float* bb1 = (const float*)d_in[12];
    const float* m1 = (const float*)d_in[13];
    const float* v1 = (const float*)d_in[14];
    const float* hW1 = (const float*)d_in[15];
    const float* hb1 = (const float*)d_in[16];
    const float* hg1 = (const float*)d_in[17];
    const float* hbb1 = (const float*)d_in[18];
    const float* hm1 = (const float*)d_in[19];
    const float* hv1 = (const float*)d_in[20];
    const float* hW2 = (const float*)d_in[21];
    const float* hb2 = (const float*)d_in[22];
    const float* hg2 = (const float*)d_in[23];
    const float* hbb2 = (const float*)d_in[24];
    const float* hm2 = (const float*)d_in[25];
    const float* hv2 = (const float*)d_in[26];
    const float* hW3 = (const float*)d_in[27];
    const float* hb3 = (const float*)d_in[28];
    const float* hW4 = (const float*)d_in[29];
    const float* hb4 = (const float*)d_in[30];
    float* out = (float*)d_out;

    // workspace layout (d_ws is 16B-aligned)
    float*  bufA = (float*)d_ws;                         // N*64 floats (fp16 table lives here)
    __half* xwh  = (__half*)bufA;
    float*  bufB = bufA + (size_t)N_NODES * D;           // N*64 floats (node features)
    int*    cnt  = (int*)(bufB + (size_t)N_NODES * D);   // N
    unsigned short* ssrc = (unsigned short*)(cnt + N_NODES);  // N*cap ushorts

    // slot capacity (prefer 64; deg~Poisson(16))
    size_t used  = ((size_t)2 * N_NODES * D + N_NODES) * 4;
    int cap = 64;
    if (ws_size >= used) {
        size_t avail = (ws_size - used) / ((size_t)N_NODES * 2);
        if (avail < (size_t)cap) cap = (int)avail & ~7;  // multiple of 8
    } else {
        cap = 0;  // should not happen; avoids OOB
    }

    const int NT = 256;
    hipMemsetAsync(cnt, 0, (size_t)N_NODES * 4, stream);

    // one-pass XCD-partitioned slotted-CSR build
    scatter_cnt_kernel<<<SCAT_CHUNKS * N_PART, NT, 0, stream>>>(ei, cnt, ssrc, cap, N_EDGES);

    // layer 0
    gemm64_kernel<<<(N_NODES + 63) / 64, NT, 0, stream>>>(x, W0, cnt, xwh, N_NODES);
    agg_bn_kernel<<<(N_NODES * 64 + NT - 1) / NT, NT, 0, stream>>>(
        xwh, cnt, ssrc, cap, b0, g0, bb0, m0, v0, bufB, N_NODES);

    // layer 1
    gemm64_kernel<<<(N_NODES + 63) / 64, NT, 0, stream>>>(bufB, W1, cnt, xwh, N_NODES);
    agg_bn_kernel<<<(N_NODES * 64 + NT - 1) / NT, NT, 0, stream>>>(
        xwh, cnt, ssrc, cap, b1, g1, bb1, m1, v1, bufB, N_NODES);

    // mean pool + MLP head (fused)
    pool_head_kernel<<<NUM_GRAPHS, NT, 0, stream>>>(bufB, batch,
        hW1, hb1, hg1, hbb1, hm1, hv1,
        hW2, hb2, hg2, hbb2, hm2, hv2,
        hW3, hb3, hW4, hb4, out);
}